// Round 3
// baseline (192.299 us; speedup 1.0000x reference)
//
#include <hip/hip_runtime.h>

typedef unsigned short u16;
typedef unsigned int u32;
typedef unsigned long long u64;

#define B_      64
#define C_      512
#define NN      576        // 24*24 nodes
#define NROW    24
#define THREADS 512        // 8 waves/block; 4 blocks/CU if VGPR <= 64

__device__ __forceinline__ float bl(u32 u) {            // low bf16 -> f32
    union { u32 i; float f; } v; v.i = u << 16; return v.f;
}
__device__ __forceinline__ float bh(u32 u) {            // high bf16 -> f32
    union { u32 i; float f; } v; v.i = u & 0xFFFF0000u; return v.f;
}
__device__ __forceinline__ u16 f2b(float f) {           // f32 -> bf16 RNE
    union { float f; u32 i; } v; v.f = f;
    u32 x = v.i;
    x += 0x7fffu + ((x >> 16) & 1u);
    return (u16)(x >> 16);
}

// One block = one channel. x is NOT staged in LDS: the 5-point stencil's reuse
// lives in L1, the phase-2 re-read of the channel lives in L2/L3 (x is fully
// L3-resident at 75 MB). LDS holds only the 6 coef tables (13.9 KB), so
// occupancy is VGPR-bound: target 4 blocks/CU = 32 waves/CU.
template<bool BF>
__global__ __launch_bounds__(THREADS, 8) void fused_cache(
        const void* __restrict__ xv, const void* __restrict__ adj,
        const void* __restrict__ weight, const void* __restrict__ gamma,
        const void* __restrict__ beta, void* __restrict__ outv) {
    __shared__ float smc[6 * NN];   // cs, cu, cd, cl, cr, w  (fp32)
    __shared__ float sred[18];      // 8 sum partials, 8 sumsq partials, {sc, sh}
    const int t = threadIdx.x, ch = blockIdx.x;
    const int wave = t >> 6, lane = t & 63;

    // ---- stage stencil coefs + this channel's weights (fp32 in LDS) ----
    for (int l = t; l < NN; l += THREADS) {
        const int rr = l / NROW, lc = l - rr * NROW;
        #define ARD(k) (BF ? bl((u32)((const u16*)adj)[(u64)(k) * NN + l]) \
                           : ((const float*)adj)[(u64)(k) * NN + l])
        smc[0 * NN + l] = ARD(l);
        smc[1 * NN + l] = (rr > 0)        ? ARD(l - NROW) : 0.f;
        smc[2 * NN + l] = (rr < NROW - 1) ? ARD(l + NROW) : 0.f;
        smc[3 * NN + l] = (lc > 0)        ? ARD(l - 1)    : 0.f;
        smc[4 * NN + l] = (lc < NROW - 1) ? ARD(l + 1)    : 0.f;
        #undef ARD
        smc[5 * NN + l] = BF ? bl((u32)((const u16*)weight)[(u64)ch * NN + l])
                             : ((const float*)weight)[(u64)ch * NN + l];
    }
    __syncthreads();

    // ---- phase 1: stencil * weight straight from global (L1/L3), stats ----
    float s = 0.f, s2 = 0.f;
    #pragma unroll
    for (int i = 0; i < 3; ++i) {
        const int L = lane + 64 * i;
        if (L < 144) {
            const int n = 4 * L;
            const float4 c0 = *(const float4*)&smc[0 * NN + n];
            const float4 cu = *(const float4*)&smc[1 * NN + n];
            const float4 cd = *(const float4*)&smc[2 * NN + n];
            const float4 cl = *(const float4*)&smc[3 * NN + n];
            const float4 cr = *(const float4*)&smc[4 * NN + n];
            const float4 wv = *(const float4*)&smc[5 * NN + n];
            const int nu = (n >= NROW)     ? n - NROW : n;   // coef 0 if absent
            const int nd = (n + NROW < NN) ? n + NROW : n;
            const int il = (n >= 1)        ? n - 1    : 0;
            const int ir = (n + 4 < NN)    ? n + 4    : n;
            #pragma unroll 2
            for (int q = 0; q < 8; ++q) {
                const u32 off = (u32)((wave * 8 + q) * C_ + ch) * NN;
                float4 xc, xu, xd; float xlm, xrp;
                if (BF) {
                    const u16* xp = (const u16*)xv + off;
                    const uint2 a = *(const uint2*)(xp + n);
                    const uint2 b = *(const uint2*)(xp + nu);
                    const uint2 d = *(const uint2*)(xp + nd);
                    xc = make_float4(bl(a.x), bh(a.x), bl(a.y), bh(a.y));
                    xu = make_float4(bl(b.x), bh(b.x), bl(b.y), bh(b.y));
                    xd = make_float4(bl(d.x), bh(d.x), bl(d.y), bh(d.y));
                    xlm = bl((u32)xp[il]); xrp = bl((u32)xp[ir]);
                } else {
                    const float* xp = (const float*)xv + off;
                    xc = *(const float4*)(xp + n);
                    xu = *(const float4*)(xp + nu);
                    xd = *(const float4*)(xp + nd);
                    xlm = xp[il]; xrp = xp[ir];
                }
                const float y0 = (c0.x*xc.x + cu.x*xu.x + cd.x*xd.x + cl.x*xlm  + cr.x*xc.y) * wv.x;
                const float y1 = (c0.y*xc.y + cu.y*xu.y + cd.y*xd.y + cl.y*xc.x + cr.y*xc.z) * wv.y;
                const float y2 = (c0.z*xc.z + cu.z*xu.z + cd.z*xd.z + cl.z*xc.y + cr.z*xc.w) * wv.z;
                const float y3 = (c0.w*xc.w + cu.w*xu.w + cd.w*xd.w + cl.w*xc.z + cr.w*xrp ) * wv.w;
                s += (y0 + y1) + (y2 + y3);
                s2 = fmaf(y0, y0, s2); s2 = fmaf(y1, y1, s2);
                s2 = fmaf(y2, y2, s2); s2 = fmaf(y3, y3, s2);
            }
        }
    }

    // ---- block-local BN stats ----
    #pragma unroll
    for (int o = 32; o; o >>= 1) {
        s  += __shfl_xor(s,  o, 64);
        s2 += __shfl_xor(s2, o, 64);
    }
    if (lane == 0) { sred[wave] = s; sred[8 + wave] = s2; }
    __syncthreads();
    if (t == 0) {
        float ts = 0.f, tq = 0.f;
        #pragma unroll
        for (int w = 0; w < 8; ++w) { ts += sred[w]; tq += sred[8 + w]; }
        const float cnt = (float)(B_ * NN);
        const float m = ts / cnt;
        const float v = tq / cnt - m * m;
        const float inv = 1.0f / sqrtf(v + 1e-4f);
        const float g  = BF ? bl((u32)((const u16*)gamma)[ch]) : ((const float*)gamma)[ch];
        const float bb = BF ? bl((u32)((const u16*)beta)[ch])  : ((const float*)beta)[ch];
        const float scv = g * inv;
        sred[16] = scv; sred[17] = bb - m * scv;
    }
    __syncthreads();
    const float scv = sred[16], shv = sred[17];

    // ---- phase 2: recompute from cache-warm global, affine + LeakyReLU ----
    #pragma unroll
    for (int i = 0; i < 3; ++i) {
        const int L = lane + 64 * i;
        if (L < 144) {
            const int n = 4 * L;
            const float4 c0 = *(const float4*)&smc[0 * NN + n];
            const float4 cu = *(const float4*)&smc[1 * NN + n];
            const float4 cd = *(const float4*)&smc[2 * NN + n];
            const float4 cl = *(const float4*)&smc[3 * NN + n];
            const float4 cr = *(const float4*)&smc[4 * NN + n];
            const float4 wv = *(const float4*)&smc[5 * NN + n];
            const int nu = (n >= NROW)     ? n - NROW : n;
            const int nd = (n + NROW < NN) ? n + NROW : n;
            const int il = (n >= 1)        ? n - 1    : 0;
            const int ir = (n + 4 < NN)    ? n + 4    : n;
            #pragma unroll 2
            for (int q = 0; q < 8; ++q) {
                const u32 off = (u32)((wave * 8 + q) * C_ + ch) * NN;
                float4 xc, xu, xd; float xlm, xrp;
                if (BF) {
                    const u16* xp = (const u16*)xv + off;
                    const uint2 a = *(const uint2*)(xp + n);
                    const uint2 b = *(const uint2*)(xp + nu);
                    const uint2 d = *(const uint2*)(xp + nd);
                    xc = make_float4(bl(a.x), bh(a.x), bl(a.y), bh(a.y));
                    xu = make_float4(bl(b.x), bh(b.x), bl(b.y), bh(b.y));
                    xd = make_float4(bl(d.x), bh(d.x), bl(d.y), bh(d.y));
                    xlm = bl((u32)xp[il]); xrp = bl((u32)xp[ir]);
                } else {
                    const float* xp = (const float*)xv + off;
                    xc = *(const float4*)(xp + n);
                    xu = *(const float4*)(xp + nu);
                    xd = *(const float4*)(xp + nd);
                    xlm = xp[il]; xrp = xp[ir];
                }
                const float y0 = (c0.x*xc.x + cu.x*xu.x + cd.x*xd.x + cl.x*xlm  + cr.x*xc.y) * wv.x;
                const float y1 = (c0.y*xc.y + cu.y*xu.y + cd.y*xd.y + cl.y*xc.x + cr.y*xc.z) * wv.y;
                const float y2 = (c0.z*xc.z + cu.z*xu.z + cd.z*xd.z + cl.z*xc.y + cr.z*xc.w) * wv.z;
                const float y3 = (c0.w*xc.w + cu.w*xu.w + cd.w*xd.w + cl.w*xc.z + cr.w*xrp ) * wv.w;
                float o0 = fmaf(y0, scv, shv); o0 = (o0 >= 0.f) ? o0 : 0.2f * o0;
                float o1 = fmaf(y1, scv, shv); o1 = (o1 >= 0.f) ? o1 : 0.2f * o1;
                float o2 = fmaf(y2, scv, shv); o2 = (o2 >= 0.f) ? o2 : 0.2f * o2;
                float o3 = fmaf(y3, scv, shv); o3 = (o3 >= 0.f) ? o3 : 0.2f * o3;
                if (BF) {
                    uint2 pk;
                    pk.x = (u32)f2b(o0) | ((u32)f2b(o1) << 16);
                    pk.y = (u32)f2b(o2) | ((u32)f2b(o3) << 16);
                    *(uint2*)((u16*)outv + off + n) = pk;
                } else {
                    *(float4*)((float*)outv + off + n) = make_float4(o0, o1, o2, o3);
                }
            }
        }
    }
}

extern "C" void kernel_launch(void* const* d_in, const int* in_sizes, int n_in,
                              void* d_out, int out_size, void* d_ws, size_t ws_size,
                              hipStream_t stream) {
    const void* x      = d_in[0];
    const void* adj    = d_in[1];
    const void* weight = d_in[2];
    const void* gamma  = d_in[3];
    const void* beta   = d_in[4];
    const long long SZ_BF = (long long)B_ * C_ * NN * 2;
    if ((long long)in_sizes[0] == SZ_BF)
        fused_cache<true><<<C_, THREADS, 0, stream>>>(x, adj, weight, gamma, beta, d_out);
    else
        fused_cache<false><<<C_, THREADS, 0, stream>>>(x, adj, weight, gamma, beta, d_out);
}